// Round 7
// baseline (754.259 us; speedup 1.0000x reference)
//
#include <hip/hip_runtime.h>
#include <math.h>

// ---------------------------------------------------------------------------
// Decoder step. Inputs all f32, outputs f32. bf16 MFMA, f32 accumulate.
// Two launches:
//   setup_k : ugh-GEMM + xemb-GEMM + f32->bf16 conversions (one launch)
//   mega_k  : 512 persistent blocks, software grid barriers:
//             score(4 col-blocks/block, L2-warm A) -> softmax+ctx+pack ->
//             gi GEMM -> GRU -> fc1(tanh) -> fc2  (all in one kernel)
// Outputs (concat, f32): out (256x4096) | h_new (256x1024) | attn (256x128)
// ---------------------------------------------------------------------------

#define B_   256
#define L_   128
#define V_   4096
#define ENC_ 1024
#define DEC_ 1024
#define EMB_ 512
#define MB_  1048576ull
#define NBLK 512

typedef __bf16 bf16;
typedef __bf16 bf16x8 __attribute__((ext_vector_type(8)));
typedef __bf16 bf16x4 __attribute__((ext_vector_type(4)));
typedef float  f32x4  __attribute__((ext_vector_type(4)));

__device__ __forceinline__ float fast_tanh(float x) {
  float e = __builtin_amdgcn_exp2f(x * 2.88539008177792681472f);
  return 1.0f - 2.0f * __builtin_amdgcn_rcpf(e + 1.0f);
}
__device__ __forceinline__ float fast_sigmoid(float x) {
  return __builtin_amdgcn_rcpf(1.0f + __builtin_amdgcn_exp2f(-1.44269504088896f * x));
}

// async 16B global->LDS copy
__device__ __forceinline__ void cp16(const void* g, void* l) {
  __builtin_amdgcn_global_load_lds(
      (const __attribute__((address_space(1))) void*)g,
      (__attribute__((address_space(3))) void*)l,
      16, 0, 0);
}

// 8 f32 -> bf16x8
__device__ __forceinline__ bf16x8 ld8f(const float* f) {
  f32x4 a = *(const f32x4*)f;
  f32x4 b = *(const f32x4*)(f + 4);
  bf16x8 r;
  r[0] = (bf16)a[0]; r[1] = (bf16)a[1]; r[2] = (bf16)a[2]; r[3] = (bf16)a[3];
  r[4] = (bf16)b[0]; r[5] = (bf16)b[1]; r[6] = (bf16)b[2]; r[7] = (bf16)b[3];
  return r;
}

// Grid barrier: agent-scope acq/rel atomics give cross-XCD L2 wb/inv.
// Safe iff all blocks resident (512 blocks <= worst-case capacity, see notes).
__device__ __forceinline__ void gbar(int* bar, int idx, int n) {
  __syncthreads();
  if (threadIdx.x == 0) {
    __hip_atomic_fetch_add(&bar[idx], 1, __ATOMIC_ACQ_REL, __HIP_MEMORY_SCOPE_AGENT);
    while (__hip_atomic_load(&bar[idx], __ATOMIC_ACQUIRE, __HIP_MEMORY_SCOPE_AGENT) < n)
      __builtin_amdgcn_s_sleep(1);
  }
  __syncthreads();
}

// ---------------------------------------------------------------------------
// LDS XOR swizzle (verified 0 bank conflicts): tile slot (r, lb) holds global
// cols k0 + ((lb ^ (r&7))*8 ..). Fragment read: off = ra*64 + ((kq^(ra&7))<<3).
// ---------------------------------------------------------------------------

// 64x64-tile bf16 GEMM inner loop (global_load_lds staging, swizzled).
__device__ __forceinline__ void gemm64_bf(
    const bf16* __restrict__ A, const bf16* __restrict__ Bw, int K,
    int row0, int col0, bf16* As, bf16* Bs, f32x4 acc[4])
{
  const int t = threadIdx.x;
  const int lane = t & 63, w = t >> 6, q = lane >> 4, c16 = lane & 15;
  const int sr = t >> 3, lb = t & 7;
  for (int k0 = 0; k0 < K; k0 += 64) {
#pragma unroll
    for (int ch = 0; ch < 2; ch++) {
      int r    = ch * 32 + sr;
      int gcol = k0 + ((lb ^ (r & 7)) << 3);
      cp16(A  + (size_t)(row0 + r) * K + gcol, &As[ch * 2048 + t * 8]);
      cp16(Bw + (size_t)(col0 + r) * K + gcol, &Bs[ch * 2048 + t * 8]);
    }
    __syncthreads();
#pragma unroll
    for (int kkb = 0; kkb < 8; kkb += 4) {
      int rb = w * 16 + c16;
      bf16x8 bfr = *(const bf16x8*)&Bs[rb * 64 + (((kkb + q) ^ (rb & 7)) << 3)];
#pragma unroll
      for (int i = 0; i < 4; i++) {
        int ra = i * 16 + c16;
        bf16x8 af = *(const bf16x8*)&As[ra * 64 + (((kkb + q) ^ (ra & 7)) << 3)];
        acc[i] = __builtin_amdgcn_mfma_f32_16x16x32_bf16(af, bfr, acc[i], 0, 0, 0);
      }
    }
    __syncthreads();
  }
}

// 64x64-tile f32-input GEMM inner loop (manual staging, swizzled).
__device__ __forceinline__ void gemm64_f32(
    const float* __restrict__ A, const float* __restrict__ Brow,
    int strideA, int strideB, int kbeg, int kend, int row0,
    bf16* As, bf16* Bs, f32x4 acc[4])
{
  const int t = threadIdx.x;
  const int lane = t & 63, w = t >> 6, q = lane >> 4, c16 = lane & 15;
  const int sr = t >> 3, lb = t & 7;
  for (int k0 = kbeg; k0 < kend; k0 += 64) {
    bf16x8 va[2], vb[2];
#pragma unroll
    for (int ch = 0; ch < 2; ch++) {
      int r    = ch * 32 + sr;
      int gcol = k0 + ((lb ^ (r & 7)) << 3);
      va[ch] = ld8f(A    + (size_t)(row0 + r) * strideA + gcol);
      vb[ch] = ld8f(Brow + (size_t)r * strideB + gcol);
    }
#pragma unroll
    for (int ch = 0; ch < 2; ch++) {
      *(bf16x8*)&As[ch * 2048 + t * 8] = va[ch];
      *(bf16x8*)&Bs[ch * 2048 + t * 8] = vb[ch];
    }
    __syncthreads();
#pragma unroll
    for (int kkb = 0; kkb < 8; kkb += 4) {
      int rb = w * 16 + c16;
      bf16x8 bfr = *(const bf16x8*)&Bs[rb * 64 + (((kkb + q) ^ (rb & 7)) << 3)];
#pragma unroll
      for (int i = 0; i < 4; i++) {
        int ra = i * 16 + c16;
        bf16x8 af = *(const bf16x8*)&As[ra * 64 + (((kkb + q) ^ (ra & 7)) << 3)];
        acc[i] = __builtin_amdgcn_mfma_f32_16x16x32_bf16(af, bfr, acc[i], 0, 0, 0);
      }
    }
    __syncthreads();
  }
}

// ---------------------------------------------------------------------------
// setup_k: blocks [0,256) ugh GEMM; [256,384) xemb; [384,10624) conversion.
// ---------------------------------------------------------------------------
__global__ __launch_bounds__(256) void setup_k(
    const float* __restrict__ hidden, const float* __restrict__ W2,
    const float* __restrict__ wh, const float* __restrict__ W1_b,
    const float* __restrict__ W2_b, const float* __restrict__ gbh,
    const float* __restrict__ x, const float* __restrict__ o2e,
    const float* __restrict__ enc, const float* __restrict__ W1,
    const float* __restrict__ wi, const float* __restrict__ fc1w,
    const float* __restrict__ fc2w,
    bf16* __restrict__ enc_bf, bf16* __restrict__ W1_bf,
    bf16* __restrict__ wi_bf, bf16* __restrict__ fc1_bf,
    bf16* __restrict__ fc2_bf,
    bf16* __restrict__ u, bf16* __restrict__ gh, float* __restrict__ xe4)
{
  __shared__ __align__(16) bf16 As[64 * 64];
  __shared__ __align__(16) bf16 Bs[64 * 64];

  const int bid = blockIdx.x;
  const int t   = threadIdx.x;

  if (bid >= 384) {
    int i = bid - 384;
    const float* src; bf16* dst; int blk;
    if      (i < 8192) { src = enc;  dst = enc_bf; blk = i; }
    else if (i < 8448) { src = W1;   dst = W1_bf;  blk = i - 8192; }
    else if (i < 9600) { src = wi;   dst = wi_bf;  blk = i - 8448; }
    else if (i < 9728) { src = fc1w; dst = fc1_bf; blk = i - 9600; }
    else               { src = fc2w; dst = fc2_bf; blk = i - 9728; }
    const size_t base = (size_t)blk * 4096 + t * 16;
    const float* s = src + base;
    bf16* d = dst + base;
    *(bf16x8*)(d)     = ld8f(s);
    *(bf16x8*)(d + 8) = ld8f(s + 8);
    return;
  }

  const int lane = t & 63, w = t >> 6, q = lane >> 4, c16 = lane & 15;
  f32x4 acc[4] = {};

  if (bid < 256) {
    const int row0 = (bid >> 6) * 64;
    const int col0 = (bid & 63) * 64;
    const bool isU = (col0 < 1024);
    const float* Brow = isU ? (W2 + (size_t)col0 * 1024)
                            : (wh + (size_t)(col0 - 1024) * 1024);
    gemm64_f32(hidden, Brow, 1024, 1024, 0, 1024, row0, As, Bs, acc);

    const int gc = col0 + w * 16 + c16;
    float bias = isU ? (W1_b[gc] + W2_b[gc]) : gbh[gc - 1024];
#pragma unroll
    for (int i = 0; i < 4; i++) {
      int gr0 = row0 + i * 16 + q * 4;
#pragma unroll
      for (int r = 0; r < 4; r++) {
        float v = acc[i][r] + bias;
        if (isU) u[(size_t)(gr0 + r) * 1024 + gc] = (bf16)v;
        else     gh[(size_t)(gr0 + r) * 3072 + (gc - 1024)] = (bf16)v;
      }
    }
  } else {
    const int i3   = bid - 256;
    const int col0 = (i3 & 7) * 64;
    const int row0 = ((i3 >> 3) & 3) * 64;
    const int z    = i3 >> 5;
    gemm64_f32(x, o2e + (size_t)col0 * 4096, 4096, 4096,
               z * 1024, z * 1024 + 1024, row0, As, Bs, acc);

    const int gc = col0 + w * 16 + c16;
    float* out = xe4 + (size_t)z * 131072;
#pragma unroll
    for (int i = 0; i < 4; i++) {
      int gr0 = row0 + i * 16 + q * 4;
#pragma unroll
      for (int r = 0; r < 4; r++)
        out[(size_t)(gr0 + r) * 512 + gc] = acc[i][r];
    }
  }
}

// ---------------------------------------------------------------------------
// mega_k: 512 persistent blocks.
//  S  : block (b=bid>>1, half=bid&1) computes 4 col-blocks of score for
//       batch b (same 128 enc rows -> L2-warm re-reads) -> e_part[half]
//  SM : even blocks: softmax + context + x_emb pack -> attn, rnn_in
//  GI : blocks 0..191: gi = rnn_in @ wi^T + gru_bi  (64x64 tiles, K=1536)
//  GRU: even blocks: gates -> out_h (f32) + hnew_bf
//  FC1: blocks 0..31: t = tanh(hnew @ fc1^T + fc1_b)
//  FC2: blocks 0..255: out = t @ fc2^T + fc2_b (f32)
// ---------------------------------------------------------------------------
__global__ __launch_bounds__(256) void mega_k(
    const bf16* __restrict__ enc_bf, const bf16* __restrict__ W1_bf,
    const bf16* __restrict__ u_bf, const float* __restrict__ Vw,
    float* __restrict__ e_part,            // (2, 32768)
    const float* __restrict__ xe4, const float* __restrict__ o2eb,
    const bf16* __restrict__ wi_bf, const float* __restrict__ gru_bi,
    const bf16* __restrict__ gh_bf, const float* __restrict__ h0,
    const bf16* __restrict__ fc1_bf, const float* __restrict__ fc1_b,
    const bf16* __restrict__ fc2_bf, const float* __restrict__ fc2_b,
    bf16* __restrict__ rnn_in, bf16* __restrict__ gi_bf,
    bf16* __restrict__ hnew_bf, bf16* __restrict__ tbuf,
    float* __restrict__ attn_out, float* __restrict__ out_h,
    float* __restrict__ out_main, int* __restrict__ bar)
{
  __shared__ __align__(16) bf16 As[128 * 64];   // 16 KB (64-tile stages use 1st half)
  __shared__ __align__(16) bf16 Bs[128 * 64];   // 16 KB
  __shared__ float s_misc[256];

  const int bid  = blockIdx.x;
  const int t    = threadIdx.x;
  const int lane = t & 63;
  const int w    = t >> 6;
  const int wm   = w >> 1;
  const int wn   = w & 1;
  const int q    = lane >> 4;
  const int c16  = lane & 15;
  const int sr   = t >> 3;
  const int lb   = t & 7;

  // ================= Stage S: score =================
  {
    const int b    = bid >> 1;
    const int half = bid & 1;
    const int row0 = b * 128;
    float rowsum[4][4] = {};

#pragma unroll 1
    for (int cb = half * 4; cb < half * 4 + 4; cb++) {
      const int col0 = cb * 128;
      f32x4 acc[4][4] = {};

      for (int k0 = 0; k0 < 1024; k0 += 64) {
#pragma unroll
        for (int ch = 0; ch < 4; ch++) {
          int r    = ch * 32 + sr;
          int gcol = k0 + ((lb ^ (r & 7)) << 3);
          cp16(enc_bf + (size_t)(row0 + r) * 1024 + gcol, &As[ch * 2048 + t * 8]);
          cp16(W1_bf  + (size_t)(col0 + r) * 1024 + gcol, &Bs[ch * 2048 + t * 8]);
        }
        __syncthreads();
#pragma unroll
        for (int kkb = 0; kkb < 8; kkb += 4) {
          bf16x8 af[4], bfr[4];
#pragma unroll
          for (int i = 0; i < 4; i++) {
            int ra = wm * 64 + i * 16 + c16;
            af[i] = *(const bf16x8*)&As[ra * 64 + (((kkb + q) ^ (ra & 7)) << 3)];
          }
#pragma unroll
          for (int j = 0; j < 4; j++) {
            int rb = wn * 64 + j * 16 + c16;
            bfr[j] = *(const bf16x8*)&Bs[rb * 64 + (((kkb + q) ^ (rb & 7)) << 3)];
          }
#pragma unroll
          for (int i = 0; i < 4; i++)
#pragma unroll
            for (int j = 0; j < 4; j++)
              acc[i][j] = __builtin_amdgcn_mfma_f32_16x16x32_bf16(af[i], bfr[j], acc[i][j], 0, 0, 0);
        }
        __syncthreads();
      }

#pragma unroll
      for (int i = 0; i < 4; i++)
#pragma unroll
        for (int j = 0; j < 4; j++) {
          int gc   = col0 + wn * 64 + j * 16 + c16;
          float uc = (float)u_bf[b * 1024 + gc];
          float vw = Vw[gc];
#pragma unroll
          for (int r = 0; r < 4; r++)
            rowsum[i][r] += fast_tanh(acc[i][j][r] + uc) * vw;
        }
    }

#pragma unroll
    for (int i = 0; i < 4; i++)
#pragma unroll
      for (int r = 0; r < 4; r++) {
        float v = rowsum[i][r];
        v += __shfl_xor(v, 1);
        v += __shfl_xor(v, 2);
        v += __shfl_xor(v, 4);
        v += __shfl_xor(v, 8);
        if (c16 == 0) s_misc[wn * 128 + wm * 64 + i * 16 + q * 4 + r] = v;
      }
    __syncthreads();
    if (t < 128)
      e_part[(size_t)half * 32768 + row0 + t] = s_misc[t] + s_misc[128 + t];
  }

  gbar(bar, 0, NBLK);

  // ================= Stage SM: softmax + context + pack =================
  if ((bid & 1) == 0) {
    const int b = bid >> 1;
    if (t < 128)
      s_misc[t] = e_part[b * 128 + t] + e_part[32768 + b * 128 + t];
    __syncthreads();

    float m = -1e30f;
    for (int l = 0; l < 128; l++) m = fmaxf(m, s_misc[l]);
    float sum = 0.0f;
    for (int l = 0; l < 128; l++) sum += expf(s_misc[l] - m);
    float inv = 1.0f / sum;
    __syncthreads();
    if (t < 128) {
      float p = expf(s_misc[t] - m) * inv;
      attn_out[b * 128 + t] = p;
      s_misc[t] = p;
    }
    __syncthreads();

    float a0 = 0, a1 = 0, a2 = 0, a3 = 0;
    const bf16* ep = enc_bf + (size_t)b * L_ * ENC_ + t * 4;
    for (int l = 0; l < 128; l++) {
      float p = s_misc[l];
      bf16x4 v = *(const bf16x4*)(ep + (size_t)l * ENC_);
      a0 += p * (float)v[0]; a1 += p * (float)v[1];
      a2 += p * (float)v[2]; a3 += p * (float)v[3];
    }
    bf16x4 o;
    o[0] = (bf16)a0; o[1] = (bf16)a1; o[2] = (bf16)a2; o[3] = (bf16)a3;
    *(bf16x4*)(rnn_in + (size_t)b * 1536 + t * 4) = o;

#pragma unroll
    for (int jj = 0; jj < 2; jj++) {
      int j = jj * 256 + t;
      float v = o2eb[j];
#pragma unroll
      for (int z = 0; z < 4; z++) v += xe4[(size_t)z * 131072 + b * 512 + j];
      rnn_in[(size_t)b * 1536 + 1024 + j] = (bf16)v;
    }
  }

  gbar(bar, 1, NBLK);

  // ================= Stage GI: gi GEMM (192 tiles) =================
  if (bid < 192) {
    const int col0 = (bid % 48) * 64;
    const int row0 = (bid / 48) * 64;
    f32x4 acc[4] = {};
    gemm64_bf(rnn_in, wi_bf, 1536, row0, col0, As, Bs, acc);
    const int gc = col0 + w * 16 + c16;
    float bias = gru_bi[gc];
#pragma unroll
    for (int i = 0; i < 4; i++) {
      int gr0 = row0 + i * 16 + q * 4;
#pragma unroll
      for (int r = 0; r < 4; r++)
        gi_bf[(size_t)(gr0 + r) * 3072 + gc] = (bf16)(acc[i][r] + bias);
    }
  }

  gbar(bar, 2, NBLK);

  // ================= Stage GRU =================
  if ((bid & 1) == 0) {
    const int b = bid >> 1;
    const bf16* gib = gi_bf + (size_t)b * 3072;
    const bf16* ghb = gh_bf + (size_t)b * 3072;
#pragma unroll
    for (int k = 0; k < 4; k++) {
      int d = t + k * 256;
      float ir = (float)gib[d], iz = (float)gib[1024 + d], in = (float)gib[2048 + d];
      float hr = (float)ghb[d], hz = (float)ghb[1024 + d], hn = (float)ghb[2048 + d];
      float r = fast_sigmoid(ir + hr);
      float z = fast_sigmoid(iz + hz);
      float n = fast_tanh(in + r * hn);
      float h = (1.0f - z) * n + z * h0[(size_t)b * 1024 + d];
      out_h[(size_t)b * 1024 + d] = h;
      hnew_bf[(size_t)b * 1024 + d] = (bf16)h;
    }
  }

  gbar(bar, 3, NBLK);

  // ================= Stage FC1 (32 tiles, tanh) =================
  if (bid < 32) {
    const int col0 = (bid % 8) * 64;
    const int row0 = (bid / 8) * 64;
    f32x4 acc[4] = {};
    gemm64_bf(hnew_bf, fc1_bf, 1024, row0, col0, As, Bs, acc);
    const int gc = col0 + w * 16 + c16;
    float bias = fc1_b[gc];
#pragma unroll
    for (int i = 0; i < 4; i++) {
      int gr0 = row0 + i * 16 + q * 4;
#pragma unroll
      for (int r = 0; r < 4; r++)
        tbuf[(size_t)(gr0 + r) * 512 + gc] = (bf16)fast_tanh(acc[i][r] + bias);
    }
  }

  gbar(bar, 4, NBLK);

  // ================= Stage FC2 (256 tiles, f32 out) =================
  if (bid < 256) {
    const int col0 = (bid % 64) * 64;
    const int row0 = (bid / 64) * 64;
    f32x4 acc[4] = {};
    gemm64_bf(tbuf, fc2_bf, 512, row0, col0, As, Bs, acc);
    const int gc = col0 + w * 16 + c16;
    float bias = fc2_b[gc];
#pragma unroll
    for (int i = 0; i < 4; i++) {
      int gr0 = row0 + i * 16 + q * 4;
#pragma unroll
      for (int r = 0; r < 4; r++)
        out_main[(size_t)(gr0 + r) * 4096 + gc] = acc[i][r] + bias;
    }
  }
}

// ---------------------------------------------------------------------------
extern "C" void kernel_launch(void* const* d_in, const int* in_sizes, int n_in,
                              void* d_out, int out_size, void* d_ws, size_t ws_size,
                              hipStream_t stream) {
  const float* x      = (const float*)d_in[0];
  const float* hidden = (const float*)d_in[1];
  const float* enc    = (const float*)d_in[2];
  const float* W1_w   = (const float*)d_in[3];
  const float* W1_b   = (const float*)d_in[4];
  const float* W2_w   = (const float*)d_in[5];
  const float* W2_b   = (const float*)d_in[6];
  const float* V_w    = (const float*)d_in[7];
  // d_in[8] = V_b : softmax-invariant, unused
  const float* o2e_w  = (const float*)d_in[9];
  const float* o2e_b  = (const float*)d_in[10];
  const float* gru_wi = (const float*)d_in[11];
  const float* gru_wh = (const float*)d_in[12];
  const float* gru_bi = (const float*)d_in[13];
  const float* gru_bh = (const float*)d_in[14];
  const float* fc1_w  = (const float*)d_in[15];
  const float* fc1_b  = (const float*)d_in[16];
  const float* fc2_w  = (const float*)d_in[17];
  const float* fc2_b  = (const float*)d_in[18];

  float* out_main = (float*)d_out;
  float* out_h    = out_main + (size_t)B_ * V_;
  float* out_attn = out_h + (size_t)B_ * DEC_;

  // ws layout (NEED ~88 MB; ws_size >= ~103 MB verified in R5)
  char* ws = (char*)d_ws;
  bf16*  enc_bf  = (bf16*)(ws);                          // 64 MB
  bf16*  W1_bf   = (bf16*)(ws + 64 * MB_);               // 2 MB
  bf16*  wi_bf   = (bf16*)(ws + 66 * MB_);               // 9 MB
  bf16*  fc1_bf  = (bf16*)(ws + 75 * MB_);               // 1 MB
  bf16*  fc2_bf  = (bf16*)(ws + 76 * MB_);               // 4 MB
  bf16*  u_bf    = (bf16*)(ws + 80 * MB_);               // 512 KB
  bf16*  gh_bf   = (bf16*)(ws + 80 * MB_ + 524288);      // 1.5 MB
  float* e_part  = (float*)(ws + 82 * MB_);              // 256 KB
  bf16*  gi_bf   = (bf16*)(ws + 82 * MB_ + 524288);      // 1.5 MB
  bf16*  rnn_in  = (bf16*)(ws + 84 * MB_);               // 768 KB
  bf16*  tbuf    = (bf16*)(ws + 84 * MB_ + 786432);      // 256 KB
  bf16*  hnew_bf = (bf16*)(ws + 85 * MB_);               // 512 KB
  float* xe4     = (float*)(ws + 85 * MB_ + 524288);     // 2 MB
  int*   bar     = (int*)(ws + 88 * MB_);                // 64 B

  // zero grid-barrier counters (capture-legal async memset)
  hipMemsetAsync(bar, 0, 16 * sizeof(int), stream);

  // 1. setup: ugh + xemb GEMMs overlapped with f32->bf16 conversions
  setup_k<<<10624, 256, 0, stream>>>(
      hidden, W2_w, gru_wh, W1_b, W2_b, gru_bh, x, o2e_w,
      enc, W1_w, gru_wi, fc1_w, fc2_w,
      enc_bf, W1_bf, wi_bf, fc1_bf, fc2_bf, u_bf, gh_bf, xe4);

  // 2. persistent megakernel: score -> softmax -> gi -> gru -> fc1 -> fc2
  mega_k<<<NBLK, 256, 0, stream>>>(
      enc_bf, W1_bf, u_bf, V_w, e_part, xe4, o2e_b,
      wi_bf, gru_bi, gh_bf, hidden, fc1_bf, fc1_b, fc2_bf, fc2_b,
      rnn_in, gi_bf, hnew_bf, tbuf, out_attn, out_h, out_main, bar);
}